// Round 9
// baseline (179.915 us; speedup 1.0000x reference)
//
#include <hip/hip_runtime.h>
#include <hip/hip_bf16.h>
#include <cstddef>

typedef __attribute__((ext_vector_type(8))) short short8;
typedef __attribute__((ext_vector_type(4))) float f32x4;

__device__ inline unsigned short f2bf(float f) {
  unsigned int u = __float_as_uint(f);
  u += 0x7fffu + ((u >> 16) & 1u);
  return (unsigned short)(u >> 16);
}
__device__ inline unsigned int pkbf(float a, float b) {
  __hip_bfloat162 h = __float22bfloat162_rn(make_float2(a, b));
  union { __hip_bfloat162 h2; unsigned int u; } cv;
  cv.h2 = h;
  return cv.u;
}

// transpose + cast: src [R,C] f32 -> dst [C,R] bf16
__global__ __launch_bounds__(256) void tcast_kernel(const float* __restrict__ src,
                                                    unsigned short* __restrict__ dst,
                                                    int R, int C) {
  __shared__ float tile[64][65];
  int c0 = blockIdx.x * 64, r0 = blockIdx.y * 64;
  int tx = threadIdx.x & 63, ty = threadIdx.x >> 6;
  for (int i = ty; i < 64; i += 4)
    tile[i][tx] = src[(size_t)(r0 + i) * C + c0 + tx];
  __syncthreads();
  for (int i = ty; i < 64; i += 4)
    dst[(size_t)(c0 + i) * R + r0 + tx] = f2bf(tile[tx][i]);
}

// pack key mask into 64-bit words: mpk[g] bit i = (mask[g*64+i] != 0)
__global__ __launch_bounds__(64) void maskpack_kernel(const int* __restrict__ mask,
                                                      unsigned long long* __restrict__ mpk) {
  int gid = blockIdx.x * 64 + threadIdx.x;
  unsigned long long bal = __ballot(mask[gid] != 0);
  if (threadIdx.x == 0) mpk[blockIdx.x] = bal;
}

// C = A[M,K] * Bt[N,K]^T. Block tile (MT*32) x 128, 4 waves 2x2.
// Single LDS buffer + reg prefetch: bar(WAR) -> ds_write -> bar(RAW) ->
// issue next global loads (named regs, no lambdas/asm: scratch-safe) ->
// compute. Global latency hides under the MFMA phase.
// MODE 0: C0 bf16 [M,N] scaled by oscale
// MODE 1: split kv: col<512 -> C0 bf16 [M,512]; col>=512 -> C1 vt[b,h,d,m]
// MODE 2: C0 f32 [M,N] + bias
template <int MT, int MODE, bool AF32>
__global__ __launch_bounds__(256) void gemm_kernel(
    const void* __restrict__ Ap, const unsigned short* __restrict__ Bt,
    void* __restrict__ C0, unsigned short* __restrict__ C1,
    const float* __restrict__ bias, int M, int N, int K, float oscale) {
  __shared__ unsigned short As[MT * 32][72];
  __shared__ unsigned short Bs[128][72];
  const int bm = blockIdx.y * (MT * 32), bn = blockIdx.x * 128;
  const int tid = threadIdx.x;
  const int wave = tid >> 6, lane = tid & 63;
  const int wr = (wave >> 1) * (MT * 16), wc = (wave & 1) * 64;
  const int l15 = lane & 15, lq = lane >> 4;
  const int sr = tid >> 3, sc = (tid & 7) * 8;
  f32x4 acc[MT][4] = {};

  const float* Af = (const float*)Ap;
  const unsigned short* Ab = (const unsigned short*)Ap;

  float4 fa[MT][2];
  uint4 ua[MT];
  uint4 ub[4];

  // prefetch K-chunk 0
#pragma unroll
  for (int p = 0; p < MT; ++p) {
    if constexpr (AF32) {
      fa[p][0] = *(const float4*)(Af + (size_t)(bm + sr + p * 32) * K + sc);
      fa[p][1] = *(const float4*)(Af + (size_t)(bm + sr + p * 32) * K + sc + 4);
    } else {
      ua[p] = *(const uint4*)(Ab + (size_t)(bm + sr + p * 32) * K + sc);
    }
  }
#pragma unroll
  for (int p = 0; p < 4; ++p)
    ub[p] = *(const uint4*)(Bt + (size_t)(bn + sr + p * 32) * K + sc);

  for (int k0 = 0; k0 < K; k0 += 64) {
    __syncthreads();  // WAR: all waves done reading LDS from previous step
#pragma unroll
    for (int p = 0; p < MT; ++p) {
      if constexpr (AF32) {
        uint4 u;
        u.x = pkbf(fa[p][0].x, fa[p][0].y);
        u.y = pkbf(fa[p][0].z, fa[p][0].w);
        u.z = pkbf(fa[p][1].x, fa[p][1].y);
        u.w = pkbf(fa[p][1].z, fa[p][1].w);
        *(uint4*)(&As[sr + p * 32][sc]) = u;
      } else {
        *(uint4*)(&As[sr + p * 32][sc]) = ua[p];
      }
    }
#pragma unroll
    for (int p = 0; p < 4; ++p)
      *(uint4*)(&Bs[sr + p * 32][sc]) = ub[p];
    __syncthreads();  // RAW: tile visible
    if (k0 + 64 < K) {  // prefetch next chunk; lands during compute
      const int kn = k0 + 64;
#pragma unroll
      for (int p = 0; p < MT; ++p) {
        if constexpr (AF32) {
          fa[p][0] = *(const float4*)(Af + (size_t)(bm + sr + p * 32) * K + kn + sc);
          fa[p][1] = *(const float4*)(Af + (size_t)(bm + sr + p * 32) * K + kn + sc + 4);
        } else {
          ua[p] = *(const uint4*)(Ab + (size_t)(bm + sr + p * 32) * K + kn + sc);
        }
      }
#pragma unroll
      for (int p = 0; p < 4; ++p)
        ub[p] = *(const uint4*)(Bt + (size_t)(bn + sr + p * 32) * K + kn + sc);
    }
#pragma unroll
    for (int kk = 0; kk < 2; ++kk) {
      short8 af[MT], bfr[4];
#pragma unroll
      for (int mt = 0; mt < MT; ++mt)
        af[mt] = *(const short8*)(&As[wr + mt * 16 + l15][kk * 32 + lq * 8]);
#pragma unroll
      for (int nt = 0; nt < 4; ++nt)
        bfr[nt] = *(const short8*)(&Bs[wc + nt * 16 + l15][kk * 32 + lq * 8]);
#pragma unroll
      for (int mt = 0; mt < MT; ++mt)
#pragma unroll
        for (int nt = 0; nt < 4; ++nt)
          acc[mt][nt] = __builtin_amdgcn_mfma_f32_16x16x32_bf16(af[mt], bfr[nt], acc[mt][nt], 0, 0, 0);
    }
  }

#pragma unroll
  for (int mt = 0; mt < MT; ++mt)
#pragma unroll
    for (int nt = 0; nt < 4; ++nt) {
      int row0 = bm + wr + mt * 16 + lq * 4;
      int col = bn + wc + nt * 16 + l15;
      if constexpr (MODE == 1) {
        if (col >= 512) {  // V^T path: 4 consecutive m -> one 8B store
          int bb = row0 >> 11, m = row0 & 2047;
          int hd = col - 512;  // h*64+d
          uint2 w;
          w.x = pkbf(acc[mt][nt][0], acc[mt][nt][1]);
          w.y = pkbf(acc[mt][nt][2], acc[mt][nt][3]);
          *(uint2*)(C1 + ((size_t)bb * 512 + hd) * 2048 + m) = w;
          continue;
        }
      }
#pragma unroll
      for (int j = 0; j < 4; ++j) {
        int row = row0 + j;
        float v = acc[mt][nt][j];
        if constexpr (MODE == 0) {
          ((unsigned short*)C0)[(size_t)row * N + col] = f2bf(v * oscale);
        } else if constexpr (MODE == 1) {
          ((unsigned short*)C0)[(size_t)row * 512 + col] = f2bf(v);
        } else {
          ((float*)C0)[(size_t)row * N + col] = v + bias[col];
        }
      }
    }
}

// Flash attention, swapped-MFMA in-register softmax, PERMUTED-K layout:
// key g staged at LDS row p(g) so that acc position (ct,lq,j) holds key
// kappa = (j>>1)*32 + lq*8 + 2ct + (j&1). Then the PV B-fragment for
// subtile kk is simply {xp[0][kk],xp[1][kk],xp[2][kk],xp[3][kk]} where
// xp[ct][half] = pkbf(exp(s[ct][2*half]), exp(s[ct][2*half+1])) -- the
// 16 ds_bpermute + 8 selects of the old redistribution are GONE.
// Double-buffered LDS, ONE __syncthreads per KV-tile, no asm/lambdas.
// 8 waves x 16 q-rows = 128 q-rows/block; 512 thr.
// T13 defer-rescale: wave-uniform skip of o-rescale when no row max grew.
__global__ __launch_bounds__(512) void attn_kernel(
    const unsigned short* __restrict__ Q, const unsigned short* __restrict__ Kb,
    const unsigned short* __restrict__ Vt, const unsigned long long* __restrict__ Mpk,
    unsigned short* __restrict__ O) {
  __shared__ unsigned short Ks[2][64][72];
  __shared__ unsigned short Vs[2][64][72];
  const int b = blockIdx.x >> 3, h = blockIdx.x & 7;
  const int tid = threadIdx.x, lane = tid & 63;
  const int wave = tid >> 6;
  const int l15 = lane & 15, lq = lane >> 4;
  const int wrow = blockIdx.y * 128 + wave * 16;

  // Q fragments: lane holds q-col = l15, d-elems lq*8..+7
  short8 qf0 = *(const short8*)(Q + (size_t)(b * 2048 + wrow + l15) * 512 + h * 64 + lq * 8);
  short8 qf1 = *(const short8*)(Q + (size_t)(b * 2048 + wrow + l15) * 512 + h * 64 + 32 + lq * 8);

  f32x4 o[4] = {};  // O^T[d = dt*16+lq*4+j][q = l15]
  float mrun = -1e30f, lrun = 0.f;

  const unsigned short* Kg = Kb + (size_t)b * 2048 * 512 + h * 64;
  const unsigned short* Vg = Vt + (size_t)(b * 8 + h) * 64 * 2048;
  const unsigned long long* mp = Mpk + b * 32;

  const int str = tid >> 3;        // 0..63 (key g within tile)
  const int stc = (tid & 7) * 8;   // elem col within 64
  // permuted K row: g=(kk,lqB,m) -> row (m>>1)*16 + lqB*4 + kk*2 + (m&1)
  const int kprow = ((str & 7) >> 1) * 16 + ((str >> 3) & 3) * 4
                  + ((str >> 5) << 1) + (str & 1);
  const int msh = lq * 8;

  // prefetch tile 0 (named scalars only)
  uint4 kr = *(const uint4*)(Kg + (size_t)str * 512 + stc);
  uint4 vr = *(const uint4*)(Vg + (size_t)str * 2048 + stc);
  unsigned long long mreg = mp[0];

  for (int mb = 0; mb < 2048; mb += 64) {
    const int buf = (mb >> 6) & 1;
    // implicit vmcnt wait on kr/vr here (thread-local)
    *(uint4*)(&Ks[buf][kprow][stc]) = kr;
    *(uint4*)(&Vs[buf][str][stc]) = vr;
    unsigned long long mcur = mreg;
    __syncthreads();  // write->read sync for buf; prefetch below never crosses a barrier
    if (mb + 64 < 2048) {
      kr = *(const uint4*)(Kg + (size_t)(mb + 64 + str) * 512 + stc);
      vr = *(const uint4*)(Vg + (size_t)str * 2048 + mb + 64 + stc);
      mreg = mp[(mb >> 6) + 1];
    }

    // swapped QK^T on permuted keys: s[ct][j] = S^T[key=kappa(ct,lq,j)][q=l15]
    f32x4 s[4] = {};
#pragma unroll
    for (int ct = 0; ct < 4; ++ct) {
      short8 kf = *(const short8*)(&Ks[buf][ct * 16 + l15][lq * 8]);
      s[ct] = __builtin_amdgcn_mfma_f32_16x16x32_bf16(kf, qf0, s[ct], 0, 0, 0);
    }
#pragma unroll
    for (int ct = 0; ct < 4; ++ct) {
      short8 kf = *(const short8*)(&Ks[buf][ct * 16 + l15][32 + lq * 8]);
      s[ct] = __builtin_amdgcn_mfma_f32_16x16x32_bf16(kf, qf1, s[ct], 0, 0, 0);
    }

    // mask: key kappa(ct,lq,j) = (j>>1)*32 + lq*8 + 2ct + (j&1)
    unsigned int mlo = __builtin_amdgcn_readfirstlane((unsigned int)mcur);
    unsigned int mhi = __builtin_amdgcn_readfirstlane((unsigned int)(mcur >> 32));
#pragma unroll
    for (int ct = 0; ct < 4; ++ct) {
      unsigned int lo2 = (mlo >> (msh + 2 * ct)) & 3u;
      unsigned int hi2 = (mhi >> (msh + 2 * ct)) & 3u;
      s[ct][0] = (lo2 & 1u) ? s[ct][0] : -1e30f;
      s[ct][1] = (lo2 & 2u) ? s[ct][1] : -1e30f;
      s[ct][2] = (hi2 & 1u) ? s[ct][2] : -1e30f;
      s[ct][3] = (hi2 & 2u) ? s[ct][3] : -1e30f;
    }

    float t = -1e30f;
#pragma unroll
    for (int ct = 0; ct < 4; ++ct)
#pragma unroll
      for (int j = 0; j < 4; ++j)
        t = fmaxf(t, s[ct][j]);
    t = fmaxf(t, __shfl_xor(t, 16));
    t = fmaxf(t, __shfl_xor(t, 32));
    float mn = fmaxf(mrun, t);

    float rs = 0.f;
    unsigned int xp[4][2];  // xp[ct][half]: keys kappa(ct,lq,2*half(+1))
#pragma unroll
    for (int ct = 0; ct < 4; ++ct) {
      float p0 = __builtin_amdgcn_exp2f(s[ct][0] - mn);
      float p1 = __builtin_amdgcn_exp2f(s[ct][1] - mn);
      float p2 = __builtin_amdgcn_exp2f(s[ct][2] - mn);
      float p3 = __builtin_amdgcn_exp2f(s[ct][3] - mn);
      rs += (p0 + p1) + (p2 + p3);
      xp[ct][0] = pkbf(p0, p1);
      xp[ct][1] = pkbf(p2, p3);
    }
    rs += __shfl_xor(rs, 16);
    rs += __shfl_xor(rs, 32);

    if (__any(mn > mrun)) {  // wave-uniform; bitwise-identical to fac path
      float fac = __builtin_amdgcn_exp2f(mrun - mn);
      lrun = lrun * fac + rs;
#pragma unroll
      for (int dt = 0; dt < 4; ++dt)
#pragma unroll
        for (int j = 0; j < 4; ++j)
          o[dt][j] *= fac;
    } else {
      lrun += rs;
    }
    mrun = mn;

    // PV swapped: O^T += V^T · P^T; B-frag is lane-local now
#pragma unroll
    for (int kk = 0; kk < 2; ++kk) {
      union { unsigned int u[4]; short8 s8; } pc;
      pc.u[0] = xp[0][kk];
      pc.u[1] = xp[1][kk];
      pc.u[2] = xp[2][kk];
      pc.u[3] = xp[3][kk];
#pragma unroll
      for (int dt = 0; dt < 4; ++dt) {
        short8 vf = *(const short8*)(&Vs[buf][dt * 16 + l15][kk * 32 + lq * 8]);
        o[dt] = __builtin_amdgcn_mfma_f32_16x16x32_bf16(vf, pc.s8, o[dt], 0, 0, 0);
      }
    }
  }

  float rl = 1.0f / lrun;
  unsigned short* Orow = O + (size_t)(b * 2048 + wrow + l15) * 512 + h * 64;
#pragma unroll
  for (int dt = 0; dt < 4; ++dt) {
    *(unsigned int*)(Orow + dt * 16 + lq * 4)     = pkbf(o[dt][0] * rl, o[dt][1] * rl);
    *(unsigned int*)(Orow + dt * 16 + lq * 4 + 2) = pkbf(o[dt][2] * rl, o[dt][3] * rl);
  }
}

extern "C" void kernel_launch(void* const* d_in, const int* in_sizes, int n_in,
                              void* d_out, int out_size, void* d_ws, size_t ws_size,
                              hipStream_t stream) {
  const float* x       = (const float*)d_in[0];
  const float* context = (const float*)d_in[1];
  const int*   mask    = (const int*)d_in[2];
  const float* Wq      = (const float*)d_in[3];
  const float* Wkv     = (const float*)d_in[4];
  const float* Wo      = (const float*)d_in[5];
  const float* bo      = (const float*)d_in[6];
  float* out = (float*)d_out;

  char* ws = (char*)d_ws;
  unsigned short* Wq_t  = (unsigned short*)(ws + 0);         //  512x512  bf16
  unsigned short* Wkv_t = (unsigned short*)(ws + 524288);    // 1024x512  bf16
  unsigned short* Wo_t  = (unsigned short*)(ws + 1572864);   //  512x512  bf16
  unsigned short* qb    = (unsigned short*)(ws + 2097152);   // 8192x512  bf16
  unsigned short* kb    = (unsigned short*)(ws + 10485760);  // 8192x512  bf16
  unsigned short* vtb   = (unsigned short*)(ws + 18874368);  // (b,h,d)x2048 bf16
  unsigned short* ab    = (unsigned short*)(ws + 27262976);  // 8192x512  bf16
  unsigned long long* mpk = (unsigned long long*)(ws + 35651584);  // 128 x u64

  const float QSCALE = 0.125f * 1.44269504088896f;  // head_dim^-0.5 * log2(e)

  tcast_kernel<<<dim3(8, 8), 256, 0, stream>>>(Wq, Wq_t, 512, 512);
  tcast_kernel<<<dim3(16, 8), 256, 0, stream>>>(Wkv, Wkv_t, 512, 1024);
  tcast_kernel<<<dim3(8, 8), 256, 0, stream>>>(Wo, Wo_t, 512, 512);
  maskpack_kernel<<<dim3(128), 64, 0, stream>>>(mask, mpk);
  gemm_kernel<2, 0, true><<<dim3(4, 128), 256, 0, stream>>>(x, Wq_t, qb, nullptr, nullptr, 8192, 512, 512, QSCALE);
  gemm_kernel<4, 1, true><<<dim3(8, 64), 256, 0, stream>>>(context, Wkv_t, kb, vtb, nullptr, 8192, 1024, 512, 1.0f);
  attn_kernel<<<dim3(32, 16), 512, 0, stream>>>(qb, kb, vtb, mpk, ab);
  gemm_kernel<2, 2, false><<<dim3(4, 128), 256, 0, stream>>>(ab, Wo_t, out, nullptr, bo, 8192, 512, 512, 1.0f);
}

// Round 10
// 170.355 us; speedup vs baseline: 1.0561x; 1.0561x over previous
//
#include <hip/hip_runtime.h>
#include <hip/hip_bf16.h>
#include <cstddef>

typedef __attribute__((ext_vector_type(8))) short short8;
typedef __attribute__((ext_vector_type(4))) float f32x4;

__device__ inline unsigned short f2bf(float f) {
  unsigned int u = __float_as_uint(f);
  u += 0x7fffu + ((u >> 16) & 1u);
  return (unsigned short)(u >> 16);
}
__device__ inline unsigned int pkbf(float a, float b) {
  __hip_bfloat162 h = __float22bfloat162_rn(make_float2(a, b));
  union { __hip_bfloat162 h2; unsigned int u; } cv;
  cv.h2 = h;
  return cv.u;
}

// transpose + cast: src [R,C] f32 -> dst [C,R] bf16
__global__ __launch_bounds__(256) void tcast_kernel(const float* __restrict__ src,
                                                    unsigned short* __restrict__ dst,
                                                    int R, int C) {
  __shared__ float tile[64][65];
  int c0 = blockIdx.x * 64, r0 = blockIdx.y * 64;
  int tx = threadIdx.x & 63, ty = threadIdx.x >> 6;
  for (int i = ty; i < 64; i += 4)
    tile[i][tx] = src[(size_t)(r0 + i) * C + c0 + tx];
  __syncthreads();
  for (int i = ty; i < 64; i += 4)
    dst[(size_t)(c0 + i) * R + r0 + tx] = f2bf(tile[tx][i]);
}

// pack key mask into 64-bit words: mpk[g] bit i = (mask[g*64+i] != 0)
__global__ __launch_bounds__(64) void maskpack_kernel(const int* __restrict__ mask,
                                                      unsigned long long* __restrict__ mpk) {
  int gid = blockIdx.x * 64 + threadIdx.x;
  unsigned long long bal = __ballot(mask[gid] != 0);
  if (threadIdx.x == 0) mpk[blockIdx.x] = bal;
}

// C = A[M,K] * Bt[N,K]^T. Round-7 structure (measured fastest of r7/r8/r9):
// direct global->LDS staging, two __syncthreads per K-step, no lambdas,
// no inline asm, no reg-prefetch. MT=4: 128x128 tile, 4 waves 2x2.
// MODE 0: C0 bf16 [M,N] scaled by oscale
// MODE 1: split kv: col<512 -> C0 bf16 [M,512]; col>=512 -> C1 vt[b,h,d,m]
// MODE 2: C0 f32 [M,N] + bias
template <int MT, int MODE, bool AF32>
__global__ __launch_bounds__(256) void gemm_kernel(
    const void* __restrict__ Ap, const unsigned short* __restrict__ Bt,
    void* __restrict__ C0, unsigned short* __restrict__ C1,
    const float* __restrict__ bias, int M, int N, int K, float oscale) {
  __shared__ unsigned short As[MT * 32][72];
  __shared__ unsigned short Bs[128][72];
  const int bm = blockIdx.y * (MT * 32), bn = blockIdx.x * 128;
  const int tid = threadIdx.x;
  const int wave = tid >> 6, lane = tid & 63;
  const int wr = (wave >> 1) * (MT * 16), wc = (wave & 1) * 64;
  const int l15 = lane & 15, lq = lane >> 4;
  const int sr = tid >> 3, sc = (tid & 7) * 8;
  f32x4 acc[MT][4] = {};

  const float* Af = (const float*)Ap;
  const unsigned short* Ab = (const unsigned short*)Ap;

  for (int k0 = 0; k0 < K; k0 += 64) {
    __syncthreads();
#pragma unroll
    for (int p = 0; p < MT; ++p) {
      int r = sr + p * 32;
      if constexpr (AF32) {
        const float4 f0 = *(const float4*)(Af + (size_t)(bm + r) * K + k0 + sc);
        const float4 f1 = *(const float4*)(Af + (size_t)(bm + r) * K + k0 + sc + 4);
        uint4 u;
        u.x = pkbf(f0.x, f0.y);
        u.y = pkbf(f0.z, f0.w);
        u.z = pkbf(f1.x, f1.y);
        u.w = pkbf(f1.z, f1.w);
        *(uint4*)(&As[r][sc]) = u;
      } else {
        *(uint4*)(&As[r][sc]) = *(const uint4*)(Ab + (size_t)(bm + r) * K + k0 + sc);
      }
    }
#pragma unroll
    for (int p = 0; p < 4; ++p)
      *(uint4*)(&Bs[sr + p * 32][sc]) = *(const uint4*)(Bt + (size_t)(bn + sr + p * 32) * K + k0 + sc);
    __syncthreads();
#pragma unroll
    for (int kk = 0; kk < 2; ++kk) {
      short8 af[MT], bfr[4];
#pragma unroll
      for (int mt = 0; mt < MT; ++mt)
        af[mt] = *(const short8*)(&As[wr + mt * 16 + l15][kk * 32 + lq * 8]);
#pragma unroll
      for (int nt = 0; nt < 4; ++nt)
        bfr[nt] = *(const short8*)(&Bs[wc + nt * 16 + l15][kk * 32 + lq * 8]);
#pragma unroll
      for (int mt = 0; mt < MT; ++mt)
#pragma unroll
        for (int nt = 0; nt < 4; ++nt)
          acc[mt][nt] = __builtin_amdgcn_mfma_f32_16x16x32_bf16(af[mt], bfr[nt], acc[mt][nt], 0, 0, 0);
    }
  }

#pragma unroll
  for (int mt = 0; mt < MT; ++mt)
#pragma unroll
    for (int nt = 0; nt < 4; ++nt) {
      int row0 = bm + wr + mt * 16 + lq * 4;
      int col = bn + wc + nt * 16 + l15;
      if constexpr (MODE == 1) {
        if (col >= 512) {  // V^T path: 4 consecutive m -> one 8B store
          int bb = row0 >> 11, m = row0 & 2047;
          int hd = col - 512;  // h*64+d
          uint2 w;
          w.x = pkbf(acc[mt][nt][0], acc[mt][nt][1]);
          w.y = pkbf(acc[mt][nt][2], acc[mt][nt][3]);
          *(uint2*)(C1 + ((size_t)bb * 512 + hd) * 2048 + m) = w;
          continue;
        }
      }
#pragma unroll
      for (int j = 0; j < 4; ++j) {
        int row = row0 + j;
        float v = acc[mt][nt][j];
        if constexpr (MODE == 0) {
          ((unsigned short*)C0)[(size_t)row * N + col] = f2bf(v * oscale);
        } else if constexpr (MODE == 1) {
          ((unsigned short*)C0)[(size_t)row * 512 + col] = f2bf(v);
        } else {
          ((float*)C0)[(size_t)row * N + col] = v + bias[col];
        }
      }
    }
}

// Flash attention, swapped-MFMA in-register softmax, permuted-K layout
// (PV B-frag lane-local, no cross-lane P movement).
// Padding 74 elems/row (37 dwords, odd): rows 16 apart differ by 16 banks
// -> staging writes 2-way (free), reads conflict-free. (72 gave 4-way.)
// T13 threshold defer-max (THR=8, exp2 domain): skip o-rescale while the
// tile max stays within mrun+8; P bounded by 2^8 (bf16/f32-safe).
// Double-buffered LDS, ONE __syncthreads per KV-tile, no asm/lambdas.
// 8 waves x 16 q-rows = 128 q-rows/block; 512 thr.
__global__ __launch_bounds__(512) void attn_kernel(
    const unsigned short* __restrict__ Q, const unsigned short* __restrict__ Kb,
    const unsigned short* __restrict__ Vt, const unsigned long long* __restrict__ Mpk,
    unsigned short* __restrict__ O) {
  __shared__ unsigned short Ks[2][64][74];
  __shared__ unsigned short Vs[2][64][74];
  const int b = blockIdx.x >> 3, h = blockIdx.x & 7;
  const int tid = threadIdx.x, lane = tid & 63;
  const int wave = tid >> 6;
  const int l15 = lane & 15, lq = lane >> 4;
  const int wrow = blockIdx.y * 128 + wave * 16;

  // Q fragments: lane holds q-col = l15, d-elems lq*8..+7
  short8 qf0 = *(const short8*)(Q + (size_t)(b * 2048 + wrow + l15) * 512 + h * 64 + lq * 8);
  short8 qf1 = *(const short8*)(Q + (size_t)(b * 2048 + wrow + l15) * 512 + h * 64 + 32 + lq * 8);

  f32x4 o[4] = {};  // O^T[d = dt*16+lq*4+j][q = l15]
  float mrun = -1e30f, lrun = 0.f;

  const unsigned short* Kg = Kb + (size_t)b * 2048 * 512 + h * 64;
  const unsigned short* Vg = Vt + (size_t)(b * 8 + h) * 64 * 2048;
  const unsigned long long* mp = Mpk + b * 32;

  const int str = tid >> 3;        // 0..63 (key g within tile)
  const int stc = (tid & 7) * 8;   // elem col within 64
  // permuted K row: g=(kk,lqB,m) -> row (m>>1)*16 + lqB*4 + kk*2 + (m&1)
  const int kprow = ((str & 7) >> 1) * 16 + ((str >> 3) & 3) * 4
                  + ((str >> 5) << 1) + (str & 1);
  const int msh = lq * 8;

  // prefetch tile 0 (named scalars only)
  uint4 kr = *(const uint4*)(Kg + (size_t)str * 512 + stc);
  uint4 vr = *(const uint4*)(Vg + (size_t)str * 2048 + stc);
  unsigned long long mreg = mp[0];

  for (int mb = 0; mb < 2048; mb += 64) {
    const int buf = (mb >> 6) & 1;
    // implicit vmcnt wait on kr/vr here (thread-local)
    *(uint4*)(&Ks[buf][kprow][stc]) = kr;
    *(uint4*)(&Vs[buf][str][stc]) = vr;
    unsigned long long mcur = mreg;
    __syncthreads();  // write->read sync for buf; prefetch below never crosses a barrier
    if (mb + 64 < 2048) {
      kr = *(const uint4*)(Kg + (size_t)(mb + 64 + str) * 512 + stc);
      vr = *(const uint4*)(Vg + (size_t)str * 2048 + mb + 64 + stc);
      mreg = mp[(mb >> 6) + 1];
    }

    // swapped QK^T on permuted keys: s[ct][j] = S^T[key=kappa(ct,lq,j)][q=l15]
    // kappa = (j>>1)*32 + lq*8 + 2ct + (j&1)
    f32x4 s[4] = {};
#pragma unroll
    for (int ct = 0; ct < 4; ++ct) {
      short8 kf = *(const short8*)(&Ks[buf][ct * 16 + l15][lq * 8]);
      s[ct] = __builtin_amdgcn_mfma_f32_16x16x32_bf16(kf, qf0, s[ct], 0, 0, 0);
    }
#pragma unroll
    for (int ct = 0; ct < 4; ++ct) {
      short8 kf = *(const short8*)(&Ks[buf][ct * 16 + l15][32 + lq * 8]);
      s[ct] = __builtin_amdgcn_mfma_f32_16x16x32_bf16(kf, qf1, s[ct], 0, 0, 0);
    }

    // mask: key kappa(ct,lq,j)
    unsigned int mlo = __builtin_amdgcn_readfirstlane((unsigned int)mcur);
    unsigned int mhi = __builtin_amdgcn_readfirstlane((unsigned int)(mcur >> 32));
#pragma unroll
    for (int ct = 0; ct < 4; ++ct) {
      unsigned int lo2 = (mlo >> (msh + 2 * ct)) & 3u;
      unsigned int hi2 = (mhi >> (msh + 2 * ct)) & 3u;
      s[ct][0] = (lo2 & 1u) ? s[ct][0] : -1e30f;
      s[ct][1] = (lo2 & 2u) ? s[ct][1] : -1e30f;
      s[ct][2] = (hi2 & 1u) ? s[ct][2] : -1e30f;
      s[ct][3] = (hi2 & 2u) ? s[ct][3] : -1e30f;
    }

    float t = -1e30f;
#pragma unroll
    for (int ct = 0; ct < 4; ++ct)
#pragma unroll
      for (int j = 0; j < 4; ++j)
        t = fmaxf(t, s[ct][j]);
    t = fmaxf(t, __shfl_xor(t, 16));
    t = fmaxf(t, __shfl_xor(t, 32));
    // t = this tile's row max (replicated across the 4 lq copies of each row)

    // T13 defer: only rescale when some row grew past mrun+8
    const bool grow = !__all(t <= mrun + 8.0f);  // wave-uniform
    float fac = 1.0f;
    if (grow) {
      float mn = fmaxf(mrun, t);
      fac = __builtin_amdgcn_exp2f(mrun - mn);
      mrun = mn;
    }

    float rs = 0.f;
    unsigned int xp[4][2];  // xp[ct][half]: keys kappa(ct,lq,2*half(+1))
#pragma unroll
    for (int ct = 0; ct < 4; ++ct) {
      float p0 = __builtin_amdgcn_exp2f(s[ct][0] - mrun);
      float p1 = __builtin_amdgcn_exp2f(s[ct][1] - mrun);
      float p2 = __builtin_amdgcn_exp2f(s[ct][2] - mrun);
      float p3 = __builtin_amdgcn_exp2f(s[ct][3] - mrun);
      rs += (p0 + p1) + (p2 + p3);
      xp[ct][0] = pkbf(p0, p1);
      xp[ct][1] = pkbf(p2, p3);
    }
    rs += __shfl_xor(rs, 16);
    rs += __shfl_xor(rs, 32);

    if (grow) {
      lrun = lrun * fac + rs;
#pragma unroll
      for (int dt = 0; dt < 4; ++dt)
#pragma unroll
        for (int j = 0; j < 4; ++j)
          o[dt][j] *= fac;
    } else {
      lrun += rs;
    }

    // PV swapped: O^T += V^T · P^T; B-frag is lane-local
#pragma unroll
    for (int kk = 0; kk < 2; ++kk) {
      union { unsigned int u[4]; short8 s8; } pc;
      pc.u[0] = xp[0][kk];
      pc.u[1] = xp[1][kk];
      pc.u[2] = xp[2][kk];
      pc.u[3] = xp[3][kk];
#pragma unroll
      for (int dt = 0; dt < 4; ++dt) {
        short8 vf = *(const short8*)(&Vs[buf][dt * 16 + l15][kk * 32 + lq * 8]);
        o[dt] = __builtin_amdgcn_mfma_f32_16x16x32_bf16(vf, pc.s8, o[dt], 0, 0, 0);
      }
    }
  }

  float rl = 1.0f / lrun;
  unsigned short* Orow = O + (size_t)(b * 2048 + wrow + l15) * 512 + h * 64;
#pragma unroll
  for (int dt = 0; dt < 4; ++dt) {
    *(unsigned int*)(Orow + dt * 16 + lq * 4)     = pkbf(o[dt][0] * rl, o[dt][1] * rl);
    *(unsigned int*)(Orow + dt * 16 + lq * 4 + 2) = pkbf(o[dt][2] * rl, o[dt][3] * rl);
  }
}

extern "C" void kernel_launch(void* const* d_in, const int* in_sizes, int n_in,
                              void* d_out, int out_size, void* d_ws, size_t ws_size,
                              hipStream_t stream) {
  const float* x       = (const float*)d_in[0];
  const float* context = (const float*)d_in[1];
  const int*   mask    = (const int*)d_in[2];
  const float* Wq      = (const float*)d_in[3];
  const float* Wkv     = (const float*)d_in[4];
  const float* Wo      = (const float*)d_in[5];
  const float* bo      = (const float*)d_in[6];
  float* out = (float*)d_out;

  char* ws = (char*)d_ws;
  unsigned short* Wq_t  = (unsigned short*)(ws + 0);         //  512x512  bf16
  unsigned short* Wkv_t = (unsigned short*)(ws + 524288);    // 1024x512  bf16
  unsigned short* Wo_t  = (unsigned short*)(ws + 1572864);   //  512x512  bf16
  unsigned short* qb    = (unsigned short*)(ws + 2097152);   // 8192x512  bf16
  unsigned short* kb    = (unsigned short*)(ws + 10485760);  // 8192x512  bf16
  unsigned short* vtb   = (unsigned short*)(ws + 18874368);  // (b,h,d)x2048 bf16
  unsigned short* ab    = (unsigned short*)(ws + 27262976);  // 8192x512  bf16
  unsigned long long* mpk = (unsigned long long*)(ws + 35651584);  // 128 x u64

  const float QSCALE = 0.125f * 1.44269504088896f;  // head_dim^-0.5 * log2(e)

  tcast_kernel<<<dim3(8, 8), 256, 0, stream>>>(Wq, Wq_t, 512, 512);
  tcast_kernel<<<dim3(16, 8), 256, 0, stream>>>(Wkv, Wkv_t, 512, 1024);
  tcast_kernel<<<dim3(8, 8), 256, 0, stream>>>(Wo, Wo_t, 512, 512);
  maskpack_kernel<<<dim3(128), 64, 0, stream>>>(mask, mpk);
  gemm_kernel<4, 0, true><<<dim3(4, 64), 256, 0, stream>>>(x, Wq_t, qb, nullptr, nullptr, 8192, 512, 512, QSCALE);
  gemm_kernel<4, 1, true><<<dim3(8, 64), 256, 0, stream>>>(context, Wkv_t, kb, vtb, nullptr, 8192, 1024, 512, 1.0f);
  attn_kernel<<<dim3(32, 16), 512, 0, stream>>>(qb, kb, vtb, mpk, ab);
  gemm_kernel<4, 2, false><<<dim3(4, 64), 256, 0, stream>>>(ab, Wo_t, out, nullptr, bo, 8192, 512, 512, 1.0f);
}

// Round 11
// 137.022 us; speedup vs baseline: 1.3130x; 1.2433x over previous
//
#include <hip/hip_runtime.h>
#include <hip/hip_bf16.h>
#include <cstddef>

typedef __attribute__((ext_vector_type(8))) short short8;
typedef __attribute__((ext_vector_type(4))) float f32x4;

__device__ inline unsigned short f2bf(float f) {
  unsigned int u = __float_as_uint(f);
  u += 0x7fffu + ((u >> 16) & 1u);
  return (unsigned short)(u >> 16);
}
__device__ inline unsigned int pkbf(float a, float b) {
  __hip_bfloat162 h = __float22bfloat162_rn(make_float2(a, b));
  union { __hip_bfloat162 h2; unsigned int u; } cv;
  cv.h2 = h;
  return cv.u;
}

// Fused prep: z=0/1/2 -> transpose+cast Wq/Wkv/Wo (f32 [R,C] -> bf16 [C,R]);
// z=3 -> pack key mask into 64-bit words. All branch conditions block-uniform.
__global__ __launch_bounds__(256) void prep_kernel(
    const float* __restrict__ Wq, const float* __restrict__ Wkv,
    const float* __restrict__ Wo, const int* __restrict__ mask,
    unsigned short* __restrict__ Wq_t, unsigned short* __restrict__ Wkv_t,
    unsigned short* __restrict__ Wo_t, unsigned long long* __restrict__ mpk) {
  const int z = blockIdx.z;
  if (z == 3) {
    if (blockIdx.y != 0) return;
    int wid = blockIdx.x * 4 + (threadIdx.x >> 6);  // 0..63
    int lane = threadIdx.x & 63;
    unsigned long long b0 = __ballot(mask[wid * 64 + lane] != 0);
    if (lane == 0) mpk[wid] = b0;
    unsigned long long b1 = __ballot(mask[(wid + 64) * 64 + lane] != 0);
    if (lane == 0) mpk[wid + 64] = b1;
    return;
  }
  const float* src = (z == 0) ? Wq : (z == 1) ? Wkv : Wo;
  unsigned short* dst = (z == 0) ? Wq_t : (z == 1) ? Wkv_t : Wo_t;
  const int R = 512, C = (z == 1) ? 1024 : 512;
  if (blockIdx.x * 64 >= C) return;  // block-uniform
  __shared__ float tile[64][65];
  int c0 = blockIdx.x * 64, r0 = blockIdx.y * 64;
  int tx = threadIdx.x & 63, ty = threadIdx.x >> 6;
  for (int i = ty; i < 64; i += 4)
    tile[i][tx] = src[(size_t)(r0 + i) * C + c0 + tx];
  __syncthreads();
  for (int i = ty; i < 64; i += 4)
    dst[(size_t)(c0 + i) * R + r0 + tx] = f2bf(tile[tx][i]);
}

// C = A[M,K] * Bt[N,K]^T. Round-7 structure (measured fastest r7/r8/r9/r10):
// direct global->LDS staging, two __syncthreads per K-step, no lambdas,
// no inline asm, no reg-prefetch. MT=4: 128x128 tile, 4 waves 2x2.
// MODE 0: C0 bf16 [M,N] scaled by oscale
// MODE 1: split kv: col<512 -> C0 bf16 [M,512]; col>=512 -> C1 vt[b,h,d,m]
// MODE 2: C0 f32 [M,N] + bias
template <int MT, int MODE, bool AF32>
__global__ __launch_bounds__(256) void gemm_kernel(
    const void* __restrict__ Ap, const unsigned short* __restrict__ Bt,
    void* __restrict__ C0, unsigned short* __restrict__ C1,
    const float* __restrict__ bias, int M, int N, int K, float oscale) {
  __shared__ unsigned short As[MT * 32][72];
  __shared__ unsigned short Bs[128][72];
  const int bm = blockIdx.y * (MT * 32), bn = blockIdx.x * 128;
  const int tid = threadIdx.x;
  const int wave = tid >> 6, lane = tid & 63;
  const int wr = (wave >> 1) * (MT * 16), wc = (wave & 1) * 64;
  const int l15 = lane & 15, lq = lane >> 4;
  const int sr = tid >> 3, sc = (tid & 7) * 8;
  f32x4 acc[MT][4] = {};

  const float* Af = (const float*)Ap;
  const unsigned short* Ab = (const unsigned short*)Ap;

  for (int k0 = 0; k0 < K; k0 += 64) {
    __syncthreads();
#pragma unroll
    for (int p = 0; p < MT; ++p) {
      int r = sr + p * 32;
      if constexpr (AF32) {
        const float4 f0 = *(const float4*)(Af + (size_t)(bm + r) * K + k0 + sc);
        const float4 f1 = *(const float4*)(Af + (size_t)(bm + r) * K + k0 + sc + 4);
        uint4 u;
        u.x = pkbf(f0.x, f0.y);
        u.y = pkbf(f0.z, f0.w);
        u.z = pkbf(f1.x, f1.y);
        u.w = pkbf(f1.z, f1.w);
        *(uint4*)(&As[r][sc]) = u;
      } else {
        *(uint4*)(&As[r][sc]) = *(const uint4*)(Ab + (size_t)(bm + r) * K + k0 + sc);
      }
    }
#pragma unroll
    for (int p = 0; p < 4; ++p)
      *(uint4*)(&Bs[sr + p * 32][sc]) = *(const uint4*)(Bt + (size_t)(bn + sr + p * 32) * K + k0 + sc);
    __syncthreads();
#pragma unroll
    for (int kk = 0; kk < 2; ++kk) {
      short8 af[MT], bfr[4];
#pragma unroll
      for (int mt = 0; mt < MT; ++mt)
        af[mt] = *(const short8*)(&As[wr + mt * 16 + l15][kk * 32 + lq * 8]);
#pragma unroll
      for (int nt = 0; nt < 4; ++nt)
        bfr[nt] = *(const short8*)(&Bs[wc + nt * 16 + l15][kk * 32 + lq * 8]);
#pragma unroll
      for (int mt = 0; mt < MT; ++mt)
#pragma unroll
        for (int nt = 0; nt < 4; ++nt)
          acc[mt][nt] = __builtin_amdgcn_mfma_f32_16x16x32_bf16(af[mt], bfr[nt], acc[mt][nt], 0, 0, 0);
    }
  }

#pragma unroll
  for (int mt = 0; mt < MT; ++mt)
#pragma unroll
    for (int nt = 0; nt < 4; ++nt) {
      int row0 = bm + wr + mt * 16 + lq * 4;
      int col = bn + wc + nt * 16 + l15;
      if constexpr (MODE == 1) {
        if (col >= 512) {  // V^T path: 4 consecutive m -> one 8B store
          int bb = row0 >> 11, m = row0 & 2047;
          int hd = col - 512;  // h*64+d
          uint2 w;
          w.x = pkbf(acc[mt][nt][0], acc[mt][nt][1]);
          w.y = pkbf(acc[mt][nt][2], acc[mt][nt][3]);
          *(uint2*)(C1 + ((size_t)bb * 512 + hd) * 2048 + m) = w;
          continue;
        }
      }
#pragma unroll
      for (int j = 0; j < 4; ++j) {
        int row = row0 + j;
        float v = acc[mt][nt][j];
        if constexpr (MODE == 0) {
          ((unsigned short*)C0)[(size_t)row * N + col] = f2bf(v * oscale);
        } else if constexpr (MODE == 1) {
          ((unsigned short*)C0)[(size_t)row * 512 + col] = f2bf(v);
        } else {
          ((float*)C0)[(size_t)row * N + col] = v + bias[col];
        }
      }
    }
}

// Flash attention, swapped-MFMA in-register softmax, permuted-K layout
// (PV B-frag lane-local, no cross-lane P movement). LDS stride 72
// (empirical best: 72 -> 8.4M conflict-cycles, 74 -> 16.8M — r9 vs r10).
// T13 threshold defer-max (THR=8, exp2 domain): skip o-rescale while the
// tile max stays within mrun+8; P bounded by 2^8 (f32-safe).
// Double-buffered LDS, ONE __syncthreads per KV-tile, no asm/lambdas
// (scratch-safe: named scalars only).
// 8 waves x 16 q-rows = 128 q-rows/block; 512 thr.
// blockIdx.x = bh (fast-varying -> per-XCD K/V L2 residency).
__global__ __launch_bounds__(512) void attn_kernel(
    const unsigned short* __restrict__ Q, const unsigned short* __restrict__ Kb,
    const unsigned short* __restrict__ Vt, const unsigned long long* __restrict__ Mpk,
    unsigned short* __restrict__ O) {
  __shared__ unsigned short Ks[2][64][72];
  __shared__ unsigned short Vs[2][64][72];
  const int b = blockIdx.x >> 3, h = blockIdx.x & 7;
  const int tid = threadIdx.x, lane = tid & 63;
  const int wave = tid >> 6;
  const int l15 = lane & 15, lq = lane >> 4;
  const int wrow = blockIdx.y * 128 + wave * 16;

  // Q fragments: lane holds q-col = l15, d-elems lq*8..+7
  short8 qf0 = *(const short8*)(Q + (size_t)(b * 2048 + wrow + l15) * 512 + h * 64 + lq * 8);
  short8 qf1 = *(const short8*)(Q + (size_t)(b * 2048 + wrow + l15) * 512 + h * 64 + 32 + lq * 8);

  f32x4 o[4] = {};  // O^T[d = dt*16+lq*4+j][q = l15]
  float mrun = -1e30f, lrun = 0.f;

  const unsigned short* Kg = Kb + (size_t)b * 2048 * 512 + h * 64;
  const unsigned short* Vg = Vt + (size_t)(b * 8 + h) * 64 * 2048;
  const unsigned long long* mp = Mpk + b * 32;

  const int str = tid >> 3;        // 0..63 (key g within tile)
  const int stc = (tid & 7) * 8;   // elem col within 64
  // permuted K row: g=(kk,lqB,m) -> row (m>>1)*16 + lqB*4 + kk*2 + (m&1)
  const int kprow = ((str & 7) >> 1) * 16 + ((str >> 3) & 3) * 4
                  + ((str >> 5) << 1) + (str & 1);
  const int msh = lq * 8;

  // prefetch tile 0 (named scalars only)
  uint4 kr = *(const uint4*)(Kg + (size_t)str * 512 + stc);
  uint4 vr = *(const uint4*)(Vg + (size_t)str * 2048 + stc);
  unsigned long long mreg = mp[0];

  for (int mb = 0; mb < 2048; mb += 64) {
    const int buf = (mb >> 6) & 1;
    // implicit vmcnt wait on kr/vr here (thread-local)
    *(uint4*)(&Ks[buf][kprow][stc]) = kr;
    *(uint4*)(&Vs[buf][str][stc]) = vr;
    unsigned long long mcur = mreg;
    __syncthreads();  // write->read sync for buf; prefetch below never crosses a barrier
    if (mb + 64 < 2048) {
      kr = *(const uint4*)(Kg + (size_t)(mb + 64 + str) * 512 + stc);
      vr = *(const uint4*)(Vg + (size_t)str * 2048 + mb + 64 + stc);
      mreg = mp[(mb >> 6) + 1];
    }

    // swapped QK^T on permuted keys: s[ct][j] = S^T[key=kappa(ct,lq,j)][q=l15]
    // kappa = (j>>1)*32 + lq*8 + 2ct + (j&1)
    f32x4 s[4] = {};
#pragma unroll
    for (int ct = 0; ct < 4; ++ct) {
      short8 kf = *(const short8*)(&Ks[buf][ct * 16 + l15][lq * 8]);
      s[ct] = __builtin_amdgcn_mfma_f32_16x16x32_bf16(kf, qf0, s[ct], 0, 0, 0);
    }
#pragma unroll
    for (int ct = 0; ct < 4; ++ct) {
      short8 kf = *(const short8*)(&Ks[buf][ct * 16 + l15][32 + lq * 8]);
      s[ct] = __builtin_amdgcn_mfma_f32_16x16x32_bf16(kf, qf1, s[ct], 0, 0, 0);
    }

    // mask: key kappa(ct,lq,j)
    unsigned int mlo = __builtin_amdgcn_readfirstlane((unsigned int)mcur);
    unsigned int mhi = __builtin_amdgcn_readfirstlane((unsigned int)(mcur >> 32));
#pragma unroll
    for (int ct = 0; ct < 4; ++ct) {
      unsigned int lo2 = (mlo >> (msh + 2 * ct)) & 3u;
      unsigned int hi2 = (mhi >> (msh + 2 * ct)) & 3u;
      s[ct][0] = (lo2 & 1u) ? s[ct][0] : -1e30f;
      s[ct][1] = (lo2 & 2u) ? s[ct][1] : -1e30f;
      s[ct][2] = (hi2 & 1u) ? s[ct][2] : -1e30f;
      s[ct][3] = (hi2 & 2u) ? s[ct][3] : -1e30f;
    }

    float t = -1e30f;
#pragma unroll
    for (int ct = 0; ct < 4; ++ct)
#pragma unroll
      for (int j = 0; j < 4; ++j)
        t = fmaxf(t, s[ct][j]);
    t = fmaxf(t, __shfl_xor(t, 16));
    t = fmaxf(t, __shfl_xor(t, 32));
    // t = this tile's row max (replicated across the 4 lq copies of each row)

    // T13 defer: only rescale when some row grew past mrun+8
    const bool grow = !__all(t <= mrun + 8.0f);  // wave-uniform
    float fac = 1.0f;
    if (grow) {
      float mn = fmaxf(mrun, t);
      fac = __builtin_amdgcn_exp2f(mrun - mn);
      mrun = mn;
    }

    float rs = 0.f;
    unsigned int xp[4][2];  // xp[ct][half]: keys kappa(ct,lq,2*half(+1))
#pragma unroll
    for (int ct = 0; ct < 4; ++ct) {
      float p0 = __builtin_amdgcn_exp2f(s[ct][0] - mrun);
      float p1 = __builtin_amdgcn_exp2f(s[ct][1] - mrun);
      float p2 = __builtin_amdgcn_exp2f(s[ct][2] - mrun);
      float p3 = __builtin_amdgcn_exp2f(s[ct][3] - mrun);
      rs += (p0 + p1) + (p2 + p3);
      xp[ct][0] = pkbf(p0, p1);
      xp[ct][1] = pkbf(p2, p3);
    }
    rs += __shfl_xor(rs, 16);
    rs += __shfl_xor(rs, 32);

    if (grow) {
      lrun = lrun * fac + rs;
#pragma unroll
      for (int dt = 0; dt < 4; ++dt)
#pragma unroll
        for (int j = 0; j < 4; ++j)
          o[dt][j] *= fac;
    } else {
      lrun += rs;
    }

    // PV swapped: O^T += V^T · P^T; B-frag is lane-local
#pragma unroll
    for (int kk = 0; kk < 2; ++kk) {
      union { unsigned int u[4]; short8 s8; } pc;
      pc.u[0] = xp[0][kk];
      pc.u[1] = xp[1][kk];
      pc.u[2] = xp[2][kk];
      pc.u[3] = xp[3][kk];
#pragma unroll
      for (int dt = 0; dt < 4; ++dt) {
        short8 vf = *(const short8*)(&Vs[buf][dt * 16 + l15][kk * 32 + lq * 8]);
        o[dt] = __builtin_amdgcn_mfma_f32_16x16x32_bf16(vf, pc.s8, o[dt], 0, 0, 0);
      }
    }
  }

  float rl = 1.0f / lrun;
  unsigned short* Orow = O + (size_t)(b * 2048 + wrow + l15) * 512 + h * 64;
#pragma unroll
  for (int dt = 0; dt < 4; ++dt) {
    *(unsigned int*)(Orow + dt * 16 + lq * 4)     = pkbf(o[dt][0] * rl, o[dt][1] * rl);
    *(unsigned int*)(Orow + dt * 16 + lq * 4 + 2) = pkbf(o[dt][2] * rl, o[dt][3] * rl);
  }
}

extern "C" void kernel_launch(void* const* d_in, const int* in_sizes, int n_in,
                              void* d_out, int out_size, void* d_ws, size_t ws_size,
                              hipStream_t stream) {
  const float* x       = (const float*)d_in[0];
  const float* context = (const float*)d_in[1];
  const int*   mask    = (const int*)d_in[2];
  const float* Wq      = (const float*)d_in[3];
  const float* Wkv     = (const float*)d_in[4];
  const float* Wo      = (const float*)d_in[5];
  const float* bo      = (const float*)d_in[6];
  float* out = (float*)d_out;

  char* ws = (char*)d_ws;
  unsigned short* Wq_t  = (unsigned short*)(ws + 0);         //  512x512  bf16
  unsigned short* Wkv_t = (unsigned short*)(ws + 524288);    // 1024x512  bf16
  unsigned short* Wo_t  = (unsigned short*)(ws + 1572864);   //  512x512  bf16
  unsigned short* qb    = (unsigned short*)(ws + 2097152);   // 8192x512  bf16
  unsigned short* kb    = (unsigned short*)(ws + 10485760);  // 8192x512  bf16
  unsigned short* vtb   = (unsigned short*)(ws + 18874368);  // (b,h,d)x2048 bf16
  unsigned short* ab    = (unsigned short*)(ws + 27262976);  // 8192x512  bf16
  unsigned long long* mpk = (unsigned long long*)(ws + 35651584);  // 128 x u64

  const float QSCALE = 0.125f * 1.44269504088896f;  // head_dim^-0.5 * log2(e)

  prep_kernel<<<dim3(16, 8, 4), 256, 0, stream>>>(Wq, Wkv, Wo, mask,
                                                  Wq_t, Wkv_t, Wo_t, mpk);
  gemm_kernel<4, 0, true><<<dim3(4, 64), 256, 0, stream>>>(x, Wq_t, qb, nullptr, nullptr, 8192, 512, 512, QSCALE);
  gemm_kernel<4, 1, true><<<dim3(8, 64), 256, 0, stream>>>(context, Wkv_t, kb, vtb, nullptr, 8192, 1024, 512, 1.0f);
  attn_kernel<<<dim3(32, 16), 512, 0, stream>>>(qb, kb, vtb, mpk, ab);
  gemm_kernel<4, 2, false><<<dim3(4, 64), 256, 0, stream>>>(ab, Wo_t, out, nullptr, bo, 8192, 512, 512, 1.0f);
}